// Round 8
// baseline (151.047 us; speedup 1.0000x reference)
//
#include <hip/hip_runtime.h>

#define CCH 32
#define BCH 6
#define HH  180
#define WW  320
#define NN  (HH*WW)             // 57600
#define BATCH 32
#define RPC 8                    // rows per chunk
#define CHUNKS ((HH + RPC - 1)/RPC)   // 23 (last chunk: 4 rows)
#define THREADS 320              // 5 waves; 8 px per thread (2560 px per chunk)

typedef float f32x4 __attribute__((ext_vector_type(4)));

// Thread t owns a 2x4 pixel group (rows i,i+1; cols j..j+3, i even, j%4==0).
// Rank identity: the group's 8 pixels occupy 8 consecutive 8-aligned walk
// ranks n8 = unwalk[i*W+j], ordered quad-major:
//   n8+0..3 = (i,j),(i,j+1),(i+1,j),(i+1,j+1); n8+4..7 = same for cols j+2,j+3.
// So flat stores AND se reads are dense f32x4 in walk domain — no permute.
__global__ __launch_bounds__(THREADS, 4) void fused_flatten_deflatten(
    const float* __restrict__ latent,    // (B, C, N)
    const float* __restrict__ w_flat,    // (BCH, C)
    const float* __restrict__ b_flat,    // (BCH,)
    const float* __restrict__ w_deflat,  // (C, BCH)
    const float* __restrict__ b_deflat,  // (C,)
    const float* __restrict__ se,        // (1, C, N) walk domain
    const int*   __restrict__ unwalk,    // (N,)
    float* __restrict__ recon,           // (B, C, N)
    float* __restrict__ flat_out)        // (B, BCH, N)
{
    __shared__ float s_wf[BCH*CCH];   // [o][c]
    __shared__ float s_wd[CCH*BCH];   // [c][o]
    __shared__ float s_bf[BCH];
    __shared__ float s_bd[CCH];

    const int t  = threadIdx.x;
    const int bx = blockIdx.x;
    const int r  = bx >> 5;            // chunk (b-inner grid: consecutive blocks
    const int b  = bx & 31;            //  = same chunk across batches -> L2 share)

    if (t < BCH*CCH) { s_wf[t] = w_flat[t]; s_wd[t] = w_deflat[t]; }
    if (t < BCH)     s_bf[t] = b_flat[t];
    if (t < CCH)     s_bd[t] = b_deflat[t];
    __syncthreads();

    const int i  = RPC*r + 2*(t/80);   // even row of the 2x4 group
    if (i >= HH) return;               // partial last chunk
    const int j  = 4*(t%80);           // col, multiple of 4
    const int p  = i*WW + j;

    const int n8 = unwalk[p];          // 8-aligned base rank of the group

    const float* latb   = latent + (size_t)b * (CCH*NN) + p;
    float*       reconb = recon  + (size_t)b * (CCH*NN) + p;

    // ---- pass 1: flat = W_f @ latent + b_f.  acc[o][0..3]=row i, [4..7]=row i+1
    float acc[BCH][8];
    #pragma unroll
    for (int o = 0; o < BCH; ++o) {
        const float bo = s_bf[o];
        #pragma unroll
        for (int k = 0; k < 8; ++k) acc[o][k] = bo;
    }

    #pragma unroll 8
    for (int c = 0; c < CCH; ++c) {
        const f32x4 xt = __builtin_nontemporal_load(
            reinterpret_cast<const f32x4*>(latb + (size_t)c*NN));
        const f32x4 xb = __builtin_nontemporal_load(
            reinterpret_cast<const f32x4*>(latb + (size_t)c*NN + WW));
        #pragma unroll
        for (int o = 0; o < BCH; ++o) {
            const float w = s_wf[o*CCH + c];
            acc[o][0] += w*xt.x; acc[o][1] += w*xt.y;
            acc[o][2] += w*xt.z; acc[o][3] += w*xt.w;
            acc[o][4] += w*xb.x; acc[o][5] += w*xb.y;
            acc[o][6] += w*xb.z; acc[o][7] += w*xb.w;
        }
    }

    // ---- flat stores: rank order = quad-major (see header comment)
    float* fb = flat_out + (size_t)b * (BCH*NN) + n8;
    #pragma unroll
    for (int o = 0; o < BCH; ++o) {
        f32x4 q1; q1.x = acc[o][0]; q1.y = acc[o][1]; q1.z = acc[o][4]; q1.w = acc[o][5];
        f32x4 q2; q2.x = acc[o][2]; q2.y = acc[o][3]; q2.z = acc[o][6]; q2.w = acc[o][7];
        *reinterpret_cast<f32x4*>(fb + (size_t)o*NN)     = q1;
        *reinterpret_cast<f32x4*>(fb + (size_t)o*NN + 4) = q2;
    }

    // ---- pass 2: recon = W_d @ flat + b_d + se  (se read walk-domain, dense)
    #pragma unroll 8
    for (int c = 0; c < CCH; ++c) {
        const f32x4 sa = *reinterpret_cast<const f32x4*>(se + (size_t)c*NN + n8);
        const f32x4 sb = *reinterpret_cast<const f32x4*>(se + (size_t)c*NN + n8 + 4);
        const float bd = s_bd[c];
        // row i: (i,j)=sa.x (i,j+1)=sa.y (i,j+2)=sb.x (i,j+3)=sb.y
        float y0 = bd + sa.x, y1 = bd + sa.y, y2 = bd + sb.x, y3 = bd + sb.y;
        // row i+1: sa.z sa.w sb.z sb.w
        float y4 = bd + sa.z, y5 = bd + sa.w, y6 = bd + sb.z, y7 = bd + sb.w;
        #pragma unroll
        for (int o = 0; o < BCH; ++o) {
            const float w = s_wd[c*BCH + o];
            y0 += w*acc[o][0]; y1 += w*acc[o][1]; y2 += w*acc[o][2]; y3 += w*acc[o][3];
            y4 += w*acc[o][4]; y5 += w*acc[o][5]; y6 += w*acc[o][6]; y7 += w*acc[o][7];
        }
        f32x4 yt; yt.x = y0; yt.y = y1; yt.z = y2; yt.w = y3;
        f32x4 yb; yb.x = y4; yb.y = y5; yb.z = y6; yb.w = y7;
        __builtin_nontemporal_store(yt, reinterpret_cast<f32x4*>(reconb + (size_t)c*NN));
        __builtin_nontemporal_store(yb, reinterpret_cast<f32x4*>(reconb + (size_t)c*NN + WW));
    }
}

extern "C" void kernel_launch(void* const* d_in, const int* in_sizes, int n_in,
                              void* d_out, int out_size, void* d_ws, size_t ws_size,
                              hipStream_t stream) {
    const float* latent   = (const float*)d_in[0];
    const float* w_flat   = (const float*)d_in[1];
    const float* b_flat   = (const float*)d_in[2];
    const float* w_deflat = (const float*)d_in[3];
    const float* b_deflat = (const float*)d_in[4];
    const float* se       = (const float*)d_in[5];
    const int*   unwalk   = (const int*)d_in[7];   // d_in[6] = walk_idx (unused)

    float* recon = (float*)d_out;
    float* flat  = (float*)d_out + (size_t)BATCH * CCH * NN;

    dim3 grid(CHUNKS * BATCH);       // 23 * 32 = 736 blocks
    dim3 block(THREADS);
    fused_flatten_deflatten<<<grid, block, 0, stream>>>(
        latent, w_flat, b_flat, w_deflat, b_deflat, se, unwalk, recon, flat);
}

// Round 9
// 133.758 us; speedup vs baseline: 1.1293x; 1.1293x over previous
//
#include <hip/hip_runtime.h>

#define CCH 32
#define BCH 6
#define HH  180
#define WW  320
#define NN  (HH*WW)             // 57600
#define BATCH 32
#define RPC 8                    // rows per chunk
#define CHUNKS ((HH + RPC - 1)/RPC)   // 23 (last chunk: 4 rows)
#define THREADS 640              // 10 waves; 4 px per thread (2560 px per chunk)

typedef float f32x2 __attribute__((ext_vector_type(2)));
typedef float f32x4 __attribute__((ext_vector_type(4)));

// ---- kernel A: se_r[c][p] = se[c][unwalk-mapped(p)] + b_deflat[c]
__global__ __launch_bounds__(256) void permute_se(
    const float* __restrict__ se, const int* __restrict__ unwalk,
    const float* __restrict__ b_deflat, float* __restrict__ se_r)
{
    const int p = (blockIdx.x * 256 + threadIdx.x) * 4;
    if (p >= NN) return;
    const int i  = p / WW;
    const int j  = p % WW;                      // multiple of 4
    const int nb = unwalk[(i & ~1)*WW + j];     // 2x4-block base rank
    const int n2 = nb + 2*(i & 1);
    #pragma unroll 8
    for (int c = 0; c < CCH; ++c) {
        const f32x2 a  = *reinterpret_cast<const f32x2*>(se + (size_t)c*NN + n2);
        const f32x2 b2 = *reinterpret_cast<const f32x2*>(se + (size_t)c*NN + n2 + 4);
        const float bd = b_deflat[c];
        f32x4 v; v.x = a.x + bd; v.y = a.y + bd; v.z = b2.x + bd; v.w = b2.y + bd;
        *reinterpret_cast<f32x4*>(se_r + (size_t)c*NN + p) = v;
    }
}

// ---- main kernel: 8-row raster chunks, b-inner grid (co-running blocks share
// se_r window + flat rank-window in L2). Regular stores everywhere (write-back
// L2 assembles full lines; nt stores caused RMW amplification).
template<int SE_RASTER>
__global__ __launch_bounds__(THREADS) void fused_flatten_deflatten(
    const float* __restrict__ latent,    // (B, C, N)
    const float* __restrict__ w_flat,    // (BCH, C)
    const float* __restrict__ b_flat,    // (BCH,)
    const float* __restrict__ w_deflat,  // (C, BCH)
    const float* __restrict__ b_deflat,  // (C,)
    const float* __restrict__ se,        // se_r (ws, bias folded) if SE_RASTER else se
    const int*   __restrict__ unwalk,    // (N,)
    float* __restrict__ recon,           // (B, C, N)
    float* __restrict__ flat_out)        // (B, BCH, N)
{
    __shared__ float s_wf[BCH*CCH];   // [o][c]
    __shared__ float s_wd[CCH*BCH];   // [c][o]
    __shared__ float s_bf[BCH];
    __shared__ float s_bd[CCH];

    const int t  = threadIdx.x;
    const int bx = blockIdx.x;
    const int r  = bx >> 5;            // chunk 0..22
    const int b  = bx & 31;            // batch (inner)

    if (t < BCH*CCH) { s_wf[t] = w_flat[t]; s_wd[t] = w_deflat[t]; }
    if (t < BCH)     s_bf[t] = b_flat[t];
    if (t < CCH)     s_bd[t] = b_deflat[t];
    __syncthreads();

    const int i  = RPC*r + t/80;       // row
    if (i >= HH) return;               // partial last chunk (rows 180..183)
    const int j  = 4*(t%80);           // col (multiple of 4)
    const int p  = i*WW + j;           // 16B-aligned raster px

    // walk ranks of the 1x4 strip: {n2, n2+1, n2+4, n2+5}
    const int nb = unwalk[(i & ~1)*WW + j];
    const int n2 = nb + 2*(i & 1);

    const float* latb   = latent + (size_t)b * (CCH*NN) + p;
    float*       reconb = recon  + (size_t)b * (CCH*NN) + p;

    // ---- pass 1: flat = W_f @ latent + b_f
    float acc[BCH][4];
    #pragma unroll
    for (int o = 0; o < BCH; ++o) {
        const float bo = s_bf[o];
        acc[o][0] = bo; acc[o][1] = bo; acc[o][2] = bo; acc[o][3] = bo;
    }

    #pragma unroll 8
    for (int c = 0; c < CCH; ++c) {
        const f32x4 x = __builtin_nontemporal_load(
            reinterpret_cast<const f32x4*>(latb + (size_t)c*NN));
        #pragma unroll
        for (int o = 0; o < BCH; ++o) {
            const float w = s_wf[o*CCH + c];
            acc[o][0] += w*x.x; acc[o][1] += w*x.y;
            acc[o][2] += w*x.z; acc[o][3] += w*x.w;
        }
    }

    // ---- flat stores: ranks n2,n2+1 (cols 0,1) and n2+4,n2+5 (cols 2,3)
    float* fb = flat_out + (size_t)b * (BCH*NN) + n2;
    #pragma unroll
    for (int o = 0; o < BCH; ++o) {
        f32x2 lo; lo.x = acc[o][0]; lo.y = acc[o][1];
        f32x2 hi; hi.x = acc[o][2]; hi.y = acc[o][3];
        *reinterpret_cast<f32x2*>(fb + (size_t)o*NN)     = lo;
        *reinterpret_cast<f32x2*>(fb + (size_t)o*NN + 4) = hi;
    }

    // ---- pass 2: recon = W_d @ flat + (se + b_d)
    #pragma unroll 8
    for (int c = 0; c < CCH; ++c) {
        float y0, y1, y2, y3;
        if (SE_RASTER) {
            const f32x4 s4 = *reinterpret_cast<const f32x4*>(se + (size_t)c*NN + p);
            y0 = s4.x; y1 = s4.y; y2 = s4.z; y3 = s4.w;   // bias pre-folded
        } else {
            const f32x2 a  = *reinterpret_cast<const f32x2*>(se + (size_t)c*NN + n2);
            const f32x2 bq = *reinterpret_cast<const f32x2*>(se + (size_t)c*NN + n2 + 4);
            const float bd = s_bd[c];
            y0 = bd + a.x; y1 = bd + a.y; y2 = bd + bq.x; y3 = bd + bq.y;
        }
        #pragma unroll
        for (int o = 0; o < BCH; ++o) {
            const float w = s_wd[c*BCH + o];
            y0 += w*acc[o][0]; y1 += w*acc[o][1];
            y2 += w*acc[o][2]; y3 += w*acc[o][3];
        }
        f32x4 yv; yv.x = y0; yv.y = y1; yv.z = y2; yv.w = y3;
        *reinterpret_cast<f32x4*>(reconb + (size_t)c*NN) = yv;   // regular store
    }
}

extern "C" void kernel_launch(void* const* d_in, const int* in_sizes, int n_in,
                              void* d_out, int out_size, void* d_ws, size_t ws_size,
                              hipStream_t stream) {
    const float* latent   = (const float*)d_in[0];
    const float* w_flat   = (const float*)d_in[1];
    const float* b_flat   = (const float*)d_in[2];
    const float* w_deflat = (const float*)d_in[3];
    const float* b_deflat = (const float*)d_in[4];
    const float* se       = (const float*)d_in[5];
    const int*   unwalk   = (const int*)d_in[7];   // d_in[6] = walk_idx (unused)

    float* recon = (float*)d_out;
    float* flat  = (float*)d_out + (size_t)BATCH * CCH * NN;

    const size_t se_bytes = (size_t)CCH * NN * sizeof(float);
    dim3 grid(CHUNKS * BATCH);       // 736 blocks
    dim3 block(THREADS);

    if (ws_size >= se_bytes) {
        float* se_r = (float*)d_ws;
        permute_se<<<dim3((NN/4 + 255)/256), dim3(256), 0, stream>>>(
            se, unwalk, b_deflat, se_r);
        fused_flatten_deflatten<1><<<grid, block, 0, stream>>>(
            latent, w_flat, b_flat, w_deflat, b_deflat, se_r, unwalk, recon, flat);
    } else {
        fused_flatten_deflatten<0><<<grid, block, 0, stream>>>(
            latent, w_flat, b_flat, w_deflat, b_deflat, se, unwalk, recon, flat);
    }
}

// Round 10
// 129.409 us; speedup vs baseline: 1.1672x; 1.0336x over previous
//
#include <hip/hip_runtime.h>

#define CCH 32
#define BCH 6
#define HH  180
#define WW  320
#define NN  (HH*WW)             // 57600
#define BATCH 32
#define RPC 8                    // rows per chunk
#define CHUNKS ((HH + RPC - 1)/RPC)   // 23 (last chunk: 4 rows)
#define THREADS 640              // 10 waves; 4 px per thread
#define NXCD 8
#define GRID_MAIN (NXCD * 3 * BATCH)  // 768: each XCD gets 3 chunk-slots x 32 b

typedef float f32x2 __attribute__((ext_vector_type(2)));
typedef float f32x4 __attribute__((ext_vector_type(4)));

// ---- kernel A: se_r[c][p] = se[c][unwalk-mapped(p)] + b_deflat[c]
// c-loop split over blockIdx.y (4 ways) -> 912 waves, latency-hiding fixed.
__global__ __launch_bounds__(256) void permute_se(
    const float* __restrict__ se, const int* __restrict__ unwalk,
    const float* __restrict__ b_deflat, float* __restrict__ se_r)
{
    const int p = (blockIdx.x * 256 + threadIdx.x) * 4;
    if (p >= NN) return;
    const int i  = p / WW;
    const int j  = p % WW;                      // multiple of 4
    const int nb = unwalk[(i & ~1)*WW + j];     // 2x4-block base rank
    const int n2 = nb + 2*(i & 1);
    const int c0 = blockIdx.y * (CCH/4);        // 8 channels per block.y
    #pragma unroll
    for (int cc = 0; cc < CCH/4; ++cc) {
        const int c = c0 + cc;
        const f32x2 a  = *reinterpret_cast<const f32x2*>(se + (size_t)c*NN + n2);
        const f32x2 b2 = *reinterpret_cast<const f32x2*>(se + (size_t)c*NN + n2 + 4);
        const float bd = b_deflat[c];
        f32x4 v; v.x = a.x + bd; v.y = a.y + bd; v.z = b2.x + bd; v.w = b2.y + bd;
        *reinterpret_cast<f32x4*>(se_r + (size_t)c*NN + p) = v;
    }
}

// ---- main kernel: 8-row raster chunks. XCD-aware remap: all 32 batches of a
// given chunk land on the SAME XCD (xcd = r%8), so the shared read set
// (se_r chunk window 320 KB + unwalk 40 KB, re-read x32) stays L2-hot.
template<int SE_RASTER>
__global__ __launch_bounds__(THREADS) void fused_flatten_deflatten(
    const float* __restrict__ latent,    // (B, C, N)
    const float* __restrict__ w_flat,    // (BCH, C)
    const float* __restrict__ b_flat,    // (BCH,)
    const float* __restrict__ w_deflat,  // (C, BCH)
    const float* __restrict__ b_deflat,  // (C,)
    const float* __restrict__ se,        // se_r (ws, bias folded) if SE_RASTER else se
    const int*   __restrict__ unwalk,    // (N,)
    float* __restrict__ recon,           // (B, C, N)
    float* __restrict__ flat_out)        // (B, BCH, N)
{
    const int g    = blockIdx.x;
    const int xcd  = g & (NXCD-1);       // HW round-robin: block g -> XCD g%8
    const int idx  = g >> 3;             // 0..95 within XCD
    const int r    = xcd + NXCD*(idx >> 5);   // chunk: {xcd, xcd+8, xcd+16}
    const int b    = idx & 31;           // batch (inner: 32 same-chunk blocks/XCD)
    if (r >= CHUNKS) return;             // 32 pad blocks (r==23) exit whole-block

    __shared__ float s_wf[BCH*CCH];   // [o][c]
    __shared__ float s_wd[CCH*BCH];   // [c][o]
    __shared__ float s_bf[BCH];
    __shared__ float s_bd[CCH];

    const int t = threadIdx.x;
    if (t < BCH*CCH) { s_wf[t] = w_flat[t]; s_wd[t] = w_deflat[t]; }
    if (t < BCH)     s_bf[t] = b_flat[t];
    if (t < CCH)     s_bd[t] = b_deflat[t];
    __syncthreads();

    const int i  = RPC*r + t/80;       // row
    if (i >= HH) return;               // partial last chunk (rows 180..183)
    const int j  = 4*(t%80);           // col (multiple of 4)
    const int p  = i*WW + j;           // 16B-aligned raster px

    // walk ranks of the 1x4 strip: {n2, n2+1, n2+4, n2+5}
    const int nb = unwalk[(i & ~1)*WW + j];
    const int n2 = nb + 2*(i & 1);

    const float* latb   = latent + (size_t)b * (CCH*NN) + p;
    float*       reconb = recon  + (size_t)b * (CCH*NN) + p;

    // ---- pass 1: flat = W_f @ latent + b_f
    float acc[BCH][4];
    #pragma unroll
    for (int o = 0; o < BCH; ++o) {
        const float bo = s_bf[o];
        acc[o][0] = bo; acc[o][1] = bo; acc[o][2] = bo; acc[o][3] = bo;
    }

    #pragma unroll 8
    for (int c = 0; c < CCH; ++c) {
        const f32x4 x = __builtin_nontemporal_load(
            reinterpret_cast<const f32x4*>(latb + (size_t)c*NN));
        #pragma unroll
        for (int o = 0; o < BCH; ++o) {
            const float w = s_wf[o*CCH + c];
            acc[o][0] += w*x.x; acc[o][1] += w*x.y;
            acc[o][2] += w*x.z; acc[o][3] += w*x.w;
        }
    }

    // ---- flat stores: ranks n2,n2+1 (cols 0,1) and n2+4,n2+5 (cols 2,3)
    float* fb = flat_out + (size_t)b * (BCH*NN) + n2;
    #pragma unroll
    for (int o = 0; o < BCH; ++o) {
        f32x2 lo; lo.x = acc[o][0]; lo.y = acc[o][1];
        f32x2 hi; hi.x = acc[o][2]; hi.y = acc[o][3];
        *reinterpret_cast<f32x2*>(fb + (size_t)o*NN)     = lo;
        *reinterpret_cast<f32x2*>(fb + (size_t)o*NN + 4) = hi;
    }

    // ---- pass 2: recon = W_d @ flat + (se + b_d)
    #pragma unroll 8
    for (int c = 0; c < CCH; ++c) {
        float y0, y1, y2, y3;
        if (SE_RASTER) {
            const f32x4 s4 = *reinterpret_cast<const f32x4*>(se + (size_t)c*NN + p);
            y0 = s4.x; y1 = s4.y; y2 = s4.z; y3 = s4.w;   // bias pre-folded
        } else {
            const f32x2 a  = *reinterpret_cast<const f32x2*>(se + (size_t)c*NN + n2);
            const f32x2 bq = *reinterpret_cast<const f32x2*>(se + (size_t)c*NN + n2 + 4);
            const float bd = s_bd[c];
            y0 = bd + a.x; y1 = bd + a.y; y2 = bd + bq.x; y3 = bd + bq.y;
        }
        #pragma unroll
        for (int o = 0; o < BCH; ++o) {
            const float w = s_wd[c*BCH + o];
            y0 += w*acc[o][0]; y1 += w*acc[o][1];
            y2 += w*acc[o][2]; y3 += w*acc[o][3];
        }
        f32x4 yv; yv.x = y0; yv.y = y1; yv.z = y2; yv.w = y3;
        __builtin_nontemporal_store(yv,
            reinterpret_cast<f32x4*>(reconb + (size_t)c*NN));
    }
}

extern "C" void kernel_launch(void* const* d_in, const int* in_sizes, int n_in,
                              void* d_out, int out_size, void* d_ws, size_t ws_size,
                              hipStream_t stream) {
    const float* latent   = (const float*)d_in[0];
    const float* w_flat   = (const float*)d_in[1];
    const float* b_flat   = (const float*)d_in[2];
    const float* w_deflat = (const float*)d_in[3];
    const float* b_deflat = (const float*)d_in[4];
    const float* se       = (const float*)d_in[5];
    const int*   unwalk   = (const int*)d_in[7];   // d_in[6] = walk_idx (unused)

    float* recon = (float*)d_out;
    float* flat  = (float*)d_out + (size_t)BATCH * CCH * NN;

    const size_t se_bytes = (size_t)CCH * NN * sizeof(float);
    dim3 grid(GRID_MAIN);            // 768 blocks (32 pad-exit)
    dim3 block(THREADS);

    if (ws_size >= se_bytes) {
        float* se_r = (float*)d_ws;
        permute_se<<<dim3((NN/4 + 255)/256, 4), dim3(256), 0, stream>>>(
            se, unwalk, b_deflat, se_r);
        fused_flatten_deflatten<1><<<grid, block, 0, stream>>>(
            latent, w_flat, b_flat, w_deflat, b_deflat, se_r, unwalk, recon, flat);
    } else {
        fused_flatten_deflatten<0><<<grid, block, 0, stream>>>(
            latent, w_flat, b_flat, w_deflat, b_deflat, se, unwalk, recon, flat);
    }
}